// Round 2
// baseline (369.347 us; speedup 1.0000x reference)
//
#include <hip/hip_runtime.h>

typedef __attribute__((ext_vector_type(4))) float f32x4;
typedef __attribute__((ext_vector_type(8))) __bf16 bf16x8;

__device__ __forceinline__ unsigned short f2bf(float f) {
  unsigned int u = __float_as_uint(f);
  u += 0x7FFFu + ((u >> 16) & 1u);
  return (unsigned short)(u >> 16);
}

__device__ __forceinline__ void unpack8(uint4 u, float* v) {
  v[0] = __uint_as_float(u.x << 16); v[1] = __uint_as_float(u.x & 0xffff0000u);
  v[2] = __uint_as_float(u.y << 16); v[3] = __uint_as_float(u.y & 0xffff0000u);
  v[4] = __uint_as_float(u.z << 16); v[5] = __uint_as_float(u.z & 0xffff0000u);
  v[6] = __uint_as_float(u.w << 16); v[7] = __uint_as_float(u.w & 0xffff0000u);
}
__device__ __forceinline__ unsigned int pack2(float a, float b) {
  return (unsigned int)f2bf(a) | ((unsigned int)f2bf(b) << 16);
}

// ---------------- weight fp32 -> bf16 ----------------
__global__ __launch_bounds__(256)
void prep_weights(const float* __restrict__ wq, const float* __restrict__ wk,
                  const float* __restrict__ wv, const float* __restrict__ wo,
                  unsigned short* __restrict__ out) {
  int i = blockIdx.x * 256 + threadIdx.x;  // 4 * 65536 total
  const float* src = (i < 65536) ? wq : (i < 131072) ? wk : (i < 196608) ? wv : wo;
  out[i] = f2bf(src[i & 65535]);
}

// ---------------- GroupNorm -> hnT [b][n][c] bf16 ----------------
__global__ __launch_bounds__(256)
void groupnorm_kernel(const float* __restrict__ x, const float* __restrict__ gamma,
                      const float* __restrict__ beta, unsigned short* __restrict__ hnT) {
  const int blk = blockIdx.x;        // b*32 + g
  const int b = blk >> 5, g = blk & 31;
  const int N = 4096;
  const float* xb = x + ((size_t)b * 256 + (size_t)g * 8) * N;
  const int tid = threadIdx.x;

  float s = 0.f, ss = 0.f;
  for (int c = 0; c < 8; ++c) {
    const float* xc = xb + (size_t)c * N;
    for (int i = tid; i < N; i += 256) { float v = xc[i]; s += v; ss += v * v; }
  }
  __shared__ float rs[4], rss[4];
  for (int m = 1; m <= 32; m <<= 1) { s += __shfl_xor(s, m); ss += __shfl_xor(ss, m); }
  const int lane = tid & 63, wid = tid >> 6;
  if (lane == 0) { rs[wid] = s; rss[wid] = ss; }
  __syncthreads();
  s  = rs[0] + rs[1] + rs[2] + rs[3];
  ss = rss[0] + rss[1] + rss[2] + rss[3];
  const float mean = s * (1.f / 32768.f);
  const float var  = ss * (1.f / 32768.f) - mean * mean;
  const float rstd = rsqrtf(var + 1e-6f);

  float gk[8], bk2[8];
  #pragma unroll
  for (int c = 0; c < 8; ++c) {
    float ga = gamma[g * 8 + c] * rstd;
    gk[c]  = ga;
    bk2[c] = beta[g * 8 + c] - mean * ga;
  }
  unsigned short* outp = hnT + (size_t)b * 256 * N + g * 8;
  for (int i = tid; i < N; i += 256) {
    union { unsigned short u[8]; uint4 v; } pk;
    #pragma unroll
    for (int c = 0; c < 8; ++c) pk.u[c] = f2bf(xb[(size_t)c * N + i] * gk[c] + bk2[c]);
    *reinterpret_cast<uint4*>(outp + (size_t)i * 256) = pk.v;
  }
}

// ---------------- row softmax, in place on bf16 [4096][4096] ----------------
__global__ __launch_bounds__(256)
void softmax_kernel(unsigned short* __restrict__ S, long zStride) {
  unsigned short* row = S + (size_t)blockIdx.y * zStride + (size_t)blockIdx.x * 4096;
  const int tid = threadIdx.x;
  uint4 r0 = *reinterpret_cast<const uint4*>(row + tid * 16);
  uint4 r1 = *reinterpret_cast<const uint4*>(row + tid * 16 + 8);
  float v[16];
  unpack8(r0, v); unpack8(r1, v + 8);
  float mx = v[0];
  #pragma unroll
  for (int i = 1; i < 16; ++i) mx = fmaxf(mx, v[i]);
  __shared__ float sh[4];
  for (int m = 1; m <= 32; m <<= 1) mx = fmaxf(mx, __shfl_xor(mx, m));
  const int lane = tid & 63, wid = tid >> 6;
  if (lane == 0) sh[wid] = mx;
  __syncthreads();
  mx = fmaxf(fmaxf(sh[0], sh[1]), fmaxf(sh[2], sh[3]));
  __syncthreads();
  float s = 0.f;
  #pragma unroll
  for (int i = 0; i < 16; ++i) { v[i] = __expf(v[i] - mx); s += v[i]; }
  for (int m = 1; m <= 32; m <<= 1) s += __shfl_xor(s, m);
  if (lane == 0) sh[wid] = s;
  __syncthreads();
  s = sh[0] + sh[1] + sh[2] + sh[3];
  const float inv = 1.f / s;
  uint4 o0, o1;
  o0.x = pack2(v[0] * inv,  v[1] * inv);  o0.y = pack2(v[2] * inv,  v[3] * inv);
  o0.z = pack2(v[4] * inv,  v[5] * inv);  o0.w = pack2(v[6] * inv,  v[7] * inv);
  o1.x = pack2(v[8] * inv,  v[9] * inv);  o1.y = pack2(v[10] * inv, v[11] * inv);
  o1.z = pack2(v[12] * inv, v[13] * inv); o1.w = pack2(v[14] * inv, v[15] * inv);
  *reinterpret_cast<uint4*>(row + tid * 16)     = o0;
  *reinterpret_cast<uint4*>(row + tid * 16 + 8) = o1;
}

// ---------------- 128x128 MFMA GEMM, A [M][K] bf16, B [N][K] bf16 ----------------
// out = A * B^T (both operands K-major). Epilogue modes below.
// LDS tile layout: [128 rows][80 bytes] (4x16B data slots + 16B pad).
// No swizzle: row stride 80B => lanes sharing a slot hit banks (20*r)%32,
// colliding only at row distance 8 -> 2-way conflict (free, m136).
enum { MODE_T = 0, MODE_NAT = 1, MODE_OUT = 2 };
#define ROWB 80
#define TILEB (128 * ROWB)

template<int MODE>
__global__ __launch_bounds__(256)
void gemm128(const unsigned short* __restrict__ A, long aStrideZ,
             const unsigned short* __restrict__ B, long bStrideZ,
             void* __restrict__ Out, long oStrideZ,
             const float* __restrict__ bias,
             const float* __restrict__ resid, long rStrideZ,
             int M, int N, int K, float scale) {
  __shared__ alignas(16) unsigned char lds[2 * TILEB];  // A tile, B tile
  const int tid  = threadIdx.x;
  const int lane = tid & 63;
  const int hi   = lane >> 4;
  const int l15  = lane & 15;
  const int wid  = tid >> 6;
  const int wm = wid >> 1, wn = wid & 1;
  const int z  = blockIdx.z;
  const int m0 = blockIdx.y * 128;
  const int n0 = blockIdx.x * 128;
  const unsigned short* Az = A + (size_t)z * aStrideZ;
  const unsigned short* Bz = B + (size_t)z * bStrideZ;
  const int srow = tid >> 2, sq = tid & 3;  // stage: row, 16B-quarter

  f32x4 acc[4][4] = {};

  const int nk = K >> 5;
  for (int kt = 0; kt < nk; ++kt) {
    const int ke = kt * 32 + sq * 8;  // element offset within row
    #pragma unroll
    for (int it = 0; it < 2; ++it) {
      const int r = srow + it * 64;
      uint4 va = *reinterpret_cast<const uint4*>(Az + (size_t)(m0 + r) * K + ke);
      uint4 vb = *reinterpret_cast<const uint4*>(Bz + (size_t)(n0 + r) * K + ke);
      *reinterpret_cast<uint4*>(lds         + r * ROWB + sq * 16) = va;
      *reinterpret_cast<uint4*>(lds + TILEB + r * ROWB + sq * 16) = vb;
    }
    __syncthreads();
    bf16x8 af[4], bfr[4];
    #pragma unroll
    for (int t = 0; t < 4; ++t) {
      const int ra = wm * 64 + t * 16 + l15;
      af[t]  = *reinterpret_cast<const bf16x8*>(lds         + ra * ROWB + hi * 16);
      const int rb = wn * 64 + t * 16 + l15;
      bfr[t] = *reinterpret_cast<const bf16x8*>(lds + TILEB + rb * ROWB + hi * 16);
    }
    #pragma unroll
    for (int mt = 0; mt < 4; ++mt)
      #pragma unroll
      for (int nt = 0; nt < 4; ++nt)
        acc[mt][nt] = __builtin_amdgcn_mfma_f32_16x16x32_bf16(af[mt], bfr[nt], acc[mt][nt], 0, 0, 0);
    __syncthreads();
  }

  const int gmb = m0 + wm * 64;
  const int gnb = n0 + wn * 64;
  if constexpr (MODE == MODE_T) {
    // transposed bf16 out: O[n][m], row stride M; + bias[m]
    unsigned short* O = (unsigned short*)Out + (size_t)z * oStrideZ;
    #pragma unroll
    for (int mt = 0; mt < 4; ++mt) {
      const int gm0 = gmb + mt * 16 + 4 * hi;
      const float b0 = bias[gm0], b1 = bias[gm0 + 1], b2 = bias[gm0 + 2], b3 = bias[gm0 + 3];
      #pragma unroll
      for (int nt = 0; nt < 4; ++nt) {
        const int gn = gnb + nt * 16 + l15;
        ushort4 pk;
        pk.x = f2bf(acc[mt][nt][0] + b0);
        pk.y = f2bf(acc[mt][nt][1] + b1);
        pk.z = f2bf(acc[mt][nt][2] + b2);
        pk.w = f2bf(acc[mt][nt][3] + b3);
        *reinterpret_cast<ushort4*>(O + (size_t)gn * M + gm0) = pk;
      }
    }
  } else if constexpr (MODE == MODE_NAT) {
    // natural bf16 out: O[m][n], row stride N; val*scale + optional bias[m]
    unsigned short* O = (unsigned short*)Out + (size_t)z * oStrideZ;
    #pragma unroll
    for (int mt = 0; mt < 4; ++mt) {
      const int gm0 = gmb + mt * 16 + 4 * hi;
      #pragma unroll
      for (int nt = 0; nt < 4; ++nt) {
        const int gn = gnb + nt * 16 + l15;
        #pragma unroll
        for (int e = 0; e < 4; ++e) {
          float v = acc[mt][nt][e] * scale + (bias ? bias[gm0 + e] : 0.f);
          O[(size_t)(gm0 + e) * N + gn] = f2bf(v);
        }
      }
    }
  } else {
    // fp32 out: O[m][n] = acc + bias[m] + resid[m][n]
    float* O = (float*)Out + (size_t)z * oStrideZ;
    const float* R = resid + (size_t)z * rStrideZ;
    #pragma unroll
    for (int mt = 0; mt < 4; ++mt) {
      const int gm0 = gmb + mt * 16 + 4 * hi;
      #pragma unroll
      for (int nt = 0; nt < 4; ++nt) {
        const int gn = gnb + nt * 16 + l15;
        #pragma unroll
        for (int e = 0; e < 4; ++e) {
          size_t idx = (size_t)(gm0 + e) * N + gn;
          O[idx] = acc[mt][nt][e] + bias[gm0 + e] + R[idx];
        }
      }
    }
  }
}

__global__ void ws_too_small(float* out, float v) {
  if (threadIdx.x == 0 && blockIdx.x == 0) out[0] = v;
}

extern "C" void kernel_launch(void* const* d_in, const int* in_sizes, int n_in,
                              void* d_out, int out_size, void* d_ws, size_t ws_size,
                              hipStream_t stream) {
  const float* x     = (const float*)d_in[0];
  const float* gamma = (const float*)d_in[1];
  const float* beta  = (const float*)d_in[2];
  const float* Wq    = (const float*)d_in[3];
  const float* bq    = (const float*)d_in[4];
  const float* Wk    = (const float*)d_in[5];
  const float* bk    = (const float*)d_in[6];
  const float* Wv    = (const float*)d_in[7];
  const float* bv    = (const float*)d_in[8];
  const float* Wo    = (const float*)d_in[9];
  const float* bo    = (const float*)d_in[10];
  float* out = (float*)d_out;

  unsigned char* ws = (unsigned char*)d_ws;
  unsigned short* WB  = (unsigned short*)(ws);             // [4][256][256] bf16 (q,k,v,o)
  unsigned short* hnT = (unsigned short*)(ws + 524288);    // [4][4096][256]
  unsigned short* Qt  = (unsigned short*)(ws + 8912896);   // [4][4096][256]
  unsigned short* Kt  = (unsigned short*)(ws + 17301504);  // [4][4096][256]
  unsigned short* V   = (unsigned short*)(ws + 25690112);  // [4][256][4096]
  unsigned short* Ht  = (unsigned short*)(ws + 34078720);  // [4][4096][256]
  unsigned short* S   = (unsigned short*)(ws + 42467328);  // [nb][4096][4096]

  const size_t sbase  = 42467328;
  const size_t sbytes = 33554432;
  int nb = 0;
  if (ws_size >= sbase + 4 * sbytes) nb = 4;
  else if (ws_size >= sbase + sbytes) nb = 1;
  if (nb == 0) {
    hipMemsetAsync(d_out, 0, (size_t)out_size * 4, stream);
    ws_too_small<<<1, 64, 0, stream>>>(out, (float)ws_size);
    return;
  }

  prep_weights<<<1024, 256, 0, stream>>>(Wq, Wk, Wv, Wo, WB);
  groupnorm_kernel<<<128, 256, 0, stream>>>(x, gamma, beta, hnT);

  // QKV projections: M=256 (c_out), N=4096 (pixels), K=256 (c_in); z = batch
  gemm128<MODE_T><<<dim3(32, 2, 4), 256, 0, stream>>>(
      WB, 0, hnT, 1048576, Qt, 1048576, bq, nullptr, 0, 256, 4096, 256, 1.f);
  gemm128<MODE_T><<<dim3(32, 2, 4), 256, 0, stream>>>(
      WB + 65536, 0, hnT, 1048576, Kt, 1048576, bk, nullptr, 0, 256, 4096, 256, 1.f);
  gemm128<MODE_NAT><<<dim3(32, 2, 4), 256, 0, stream>>>(
      WB + 131072, 0, hnT, 1048576, V, 1048576, bv, nullptr, 0, 256, 4096, 256, 1.f);

  for (int done = 0; done < 4; done += nb) {
    int nbc = (4 - done < nb) ? (4 - done) : nb;
    // S[i][j] = (1/16) sum_c Qt[i][c] * Kt[j][c];  M=N=4096, K=256
    gemm128<MODE_NAT><<<dim3(32, 32, nbc), 256, 0, stream>>>(
        Qt + (size_t)done * 1048576, 1048576, Kt + (size_t)done * 1048576, 1048576,
        S, 16777216, nullptr, nullptr, 0, 4096, 4096, 256, 0.0625f);
    softmax_kernel<<<dim3(4096, nbc), 256, 0, stream>>>(S, 16777216);
    // Ht[i][c] = sum_j P[i][j] * V[c][j];  M=4096 (i), N=256 (c), K=4096 (j)
    gemm128<MODE_NAT><<<dim3(2, 32, nbc), 256, 0, stream>>>(
        S, 16777216, V + (size_t)done * 1048576, 1048576,
        Ht + (size_t)done * 1048576, 1048576, nullptr, nullptr, 0, 4096, 256, 4096, 1.f);
  }

  // out[co][n] = sum_c Wo[co][c] * Ht[n][c] + bo[co] + x;  M=256, N=4096, K=256
  gemm128<MODE_OUT><<<dim3(32, 2, 4), 256, 0, stream>>>(
      WB + 196608, 0, Ht, 1048576, out, 1048576, bo, x, 1048576, 256, 4096, 256, 1.f);
}

// Round 3
// 314.517 us; speedup vs baseline: 1.1743x; 1.1743x over previous
//
#include <hip/hip_runtime.h>

typedef __attribute__((ext_vector_type(4))) float f32x4;
typedef __attribute__((ext_vector_type(8))) __bf16 bf16x8;

__device__ __forceinline__ unsigned short f2bf(float f) {
  unsigned int u = __float_as_uint(f);
  u += 0x7FFFu + ((u >> 16) & 1u);
  return (unsigned short)(u >> 16);
}

__device__ __forceinline__ void unpack8(uint4 u, float* v) {
  v[0] = __uint_as_float(u.x << 16); v[1] = __uint_as_float(u.x & 0xffff0000u);
  v[2] = __uint_as_float(u.y << 16); v[3] = __uint_as_float(u.y & 0xffff0000u);
  v[4] = __uint_as_float(u.z << 16); v[5] = __uint_as_float(u.z & 0xffff0000u);
  v[6] = __uint_as_float(u.w << 16); v[7] = __uint_as_float(u.w & 0xffff0000u);
}
__device__ __forceinline__ unsigned int pack2(float a, float b) {
  return (unsigned int)f2bf(a) | ((unsigned int)f2bf(b) << 16);
}

__device__ __forceinline__ void gload16(const void* g, void* l) {
  __builtin_amdgcn_global_load_lds(
      (const __attribute__((address_space(1))) void*)g,
      (__attribute__((address_space(3))) void*)l, 16, 0, 0);
}

// ---------------- weight fp32 -> bf16 ----------------
__global__ __launch_bounds__(256)
void prep_weights(const float* __restrict__ wq, const float* __restrict__ wk,
                  const float* __restrict__ wv, const float* __restrict__ wo,
                  unsigned short* __restrict__ out) {
  int i = blockIdx.x * 256 + threadIdx.x;  // 4 * 65536 total
  const float* src = (i < 65536) ? wq : (i < 131072) ? wk : (i < 196608) ? wv : wo;
  out[i] = f2bf(src[i & 65535]);
}

// ---------------- GroupNorm -> hnT [b][n][c] bf16 ----------------
__global__ __launch_bounds__(256)
void groupnorm_kernel(const float* __restrict__ x, const float* __restrict__ gamma,
                      const float* __restrict__ beta, unsigned short* __restrict__ hnT) {
  const int blk = blockIdx.x;        // b*32 + g
  const int b = blk >> 5, g = blk & 31;
  const int N = 4096;
  const float* xb = x + ((size_t)b * 256 + (size_t)g * 8) * N;
  const int tid = threadIdx.x;

  float s = 0.f, ss = 0.f;
  for (int c = 0; c < 8; ++c) {
    const float* xc = xb + (size_t)c * N;
    for (int i = tid; i < N; i += 256) { float v = xc[i]; s += v; ss += v * v; }
  }
  __shared__ float rs[4], rss[4];
  for (int m = 1; m <= 32; m <<= 1) { s += __shfl_xor(s, m); ss += __shfl_xor(ss, m); }
  const int lane = tid & 63, wid = tid >> 6;
  if (lane == 0) { rs[wid] = s; rss[wid] = ss; }
  __syncthreads();
  s  = rs[0] + rs[1] + rs[2] + rs[3];
  ss = rss[0] + rss[1] + rss[2] + rss[3];
  const float mean = s * (1.f / 32768.f);
  const float var  = ss * (1.f / 32768.f) - mean * mean;
  const float rstd = rsqrtf(var + 1e-6f);

  float gk[8], bk2[8];
  #pragma unroll
  for (int c = 0; c < 8; ++c) {
    float ga = gamma[g * 8 + c] * rstd;
    gk[c]  = ga;
    bk2[c] = beta[g * 8 + c] - mean * ga;
  }
  unsigned short* outp = hnT + (size_t)b * 256 * N + g * 8;
  for (int i = tid; i < N; i += 256) {
    union { unsigned short u[8]; uint4 v; } pk;
    #pragma unroll
    for (int c = 0; c < 8; ++c) pk.u[c] = f2bf(xb[(size_t)c * N + i] * gk[c] + bk2[c]);
    *reinterpret_cast<uint4*>(outp + (size_t)i * 256) = pk.v;
  }
}

// ---------------- row softmax, in place on bf16 [4096][4096] ----------------
__global__ __launch_bounds__(256)
void softmax_kernel(unsigned short* __restrict__ S, long zStride) {
  unsigned short* row = S + (size_t)blockIdx.y * zStride + (size_t)blockIdx.x * 4096;
  const int tid = threadIdx.x;
  uint4 r0 = *reinterpret_cast<const uint4*>(row + tid * 16);
  uint4 r1 = *reinterpret_cast<const uint4*>(row + tid * 16 + 8);
  float v[16];
  unpack8(r0, v); unpack8(r1, v + 8);
  float mx = v[0];
  #pragma unroll
  for (int i = 1; i < 16; ++i) mx = fmaxf(mx, v[i]);
  __shared__ float sh[4];
  for (int m = 1; m <= 32; m <<= 1) mx = fmaxf(mx, __shfl_xor(mx, m));
  const int lane = tid & 63, wid = tid >> 6;
  if (lane == 0) sh[wid] = mx;
  __syncthreads();
  mx = fmaxf(fmaxf(sh[0], sh[1]), fmaxf(sh[2], sh[3]));
  __syncthreads();
  float s = 0.f;
  #pragma unroll
  for (int i = 0; i < 16; ++i) { v[i] = __expf(v[i] - mx); s += v[i]; }
  for (int m = 1; m <= 32; m <<= 1) s += __shfl_xor(s, m);
  if (lane == 0) sh[wid] = s;
  __syncthreads();
  s = sh[0] + sh[1] + sh[2] + sh[3];
  const float inv = 1.f / s;
  uint4 o0, o1;
  o0.x = pack2(v[0] * inv,  v[1] * inv);  o0.y = pack2(v[2] * inv,  v[3] * inv);
  o0.z = pack2(v[4] * inv,  v[5] * inv);  o0.w = pack2(v[6] * inv,  v[7] * inv);
  o1.x = pack2(v[8] * inv,  v[9] * inv);  o1.y = pack2(v[10] * inv, v[11] * inv);
  o1.z = pack2(v[12] * inv, v[13] * inv); o1.w = pack2(v[14] * inv, v[15] * inv);
  *reinterpret_cast<uint4*>(row + tid * 16)     = o0;
  *reinterpret_cast<uint4*>(row + tid * 16 + 8) = o1;
}

// ---------------- 128x128 MFMA GEMM, A [M][K] bf16, B [N][K] bf16 ----------------
// out = A * B^T (both operands K-major).
// Staging: global_load_lds width=16, double-buffered LDS (2 x (8KB A + 8KB B)),
// depth-1 prefetch: issue tile kt+1's loads, compute tile kt, one __syncthreads
// (implicit vmcnt(0)+lgkmcnt(0) drain) per K-step.
// LDS layout linear [128 rows][64B]; quarter-slot involution swizzle applied on
// BOTH the global source (qs = (lane&3)^((lane>>3)&3)) and the fragment read
// (slot = hi^((l15>>1)&3)) so slot(row,q) holds quarter q^((row>>1)&3).
enum { MODE_T = 0, MODE_NAT = 1, MODE_OUT = 2 };

template<int MODE>
__global__ __launch_bounds__(256)
void gemm128(const unsigned short* __restrict__ A, long aStrideZ,
             const unsigned short* __restrict__ B, long bStrideZ,
             void* __restrict__ Out, long oStrideZ,
             const float* __restrict__ bias,
             const float* __restrict__ resid, long rStrideZ,
             int M, int N, int K, float scale) {
  __shared__ alignas(1024) unsigned char lds[32768];  // [buf][A 8K | B 8K]
  const int tid  = threadIdx.x;
  const int lane = tid & 63;
  const int hi   = lane >> 4;
  const int l15  = lane & 15;
  const int wid  = tid >> 6;
  const int wm = wid >> 1, wn = wid & 1;
  const int z  = blockIdx.z;
  const int m0 = blockIdx.y * 128;
  const int n0 = blockIdx.x * 128;
  const unsigned short* Az = A + (size_t)z * aStrideZ;
  const unsigned short* Bz = B + (size_t)z * bStrideZ;

  // staging addresses: wave wid owns chunks c0=2*wid, c1=2*wid+1 of each tile
  const int c0 = wid * 2, c1 = wid * 2 + 1;
  const int rr = lane >> 2;                          // row within chunk
  const int qs = (lane & 3) ^ ((lane >> 3) & 3);     // swizzled source quarter
  const unsigned short* pa0 = Az + (size_t)(m0 + c0 * 16 + rr) * K + qs * 8;
  const unsigned short* pa1 = Az + (size_t)(m0 + c1 * 16 + rr) * K + qs * 8;
  const unsigned short* pb0 = Bz + (size_t)(n0 + c0 * 16 + rr) * K + qs * 8;
  const unsigned short* pb1 = Bz + (size_t)(n0 + c1 * 16 + rr) * K + qs * 8;
  unsigned char* lA0 = lds + c0 * 1024;          // + buf*16384
  unsigned char* lA1 = lds + c1 * 1024;
  unsigned char* lB0 = lds + 8192 + c0 * 1024;
  unsigned char* lB1 = lds + 8192 + c1 * 1024;

  // fragment read offsets (fixed per lane; + buf*16384 at use)
  const int slot = hi ^ ((l15 >> 1) & 3);
  int roffA[4], roffB[4];
  #pragma unroll
  for (int t = 0; t < 4; ++t) {
    roffA[t] = (wm * 64 + t * 16 + l15) * 64 + slot * 16;
    roffB[t] = 8192 + (wn * 64 + t * 16 + l15) * 64 + slot * 16;
  }

  f32x4 acc[4][4] = {};

  const int nk = K >> 5;
  // prologue: stage tile 0 into buf 0
  gload16(pa0, lA0); gload16(pa1, lA1);
  gload16(pb0, lB0); gload16(pb1, lB1);
  __syncthreads();

  int cur = 0;
  for (int kt = 0; kt < nk; ++kt) {
    if (kt + 1 < nk) {
      const size_t ko = (size_t)(kt + 1) * 32;
      const int bo = (cur ^ 1) * 16384;
      gload16(pa0 + ko, lA0 + bo); gload16(pa1 + ko, lA1 + bo);
      gload16(pb0 + ko, lB0 + bo); gload16(pb1 + ko, lB1 + bo);
    }
    const unsigned char* base = lds + cur * 16384;
    bf16x8 af[4], bfr[4];
    #pragma unroll
    for (int t = 0; t < 4; ++t) {
      af[t]  = *reinterpret_cast<const bf16x8*>(base + roffA[t]);
      bfr[t] = *reinterpret_cast<const bf16x8*>(base + roffB[t]);
    }
    #pragma unroll
    for (int mt = 0; mt < 4; ++mt)
      #pragma unroll
      for (int nt = 0; nt < 4; ++nt)
        acc[mt][nt] = __builtin_amdgcn_mfma_f32_16x16x32_bf16(af[mt], bfr[nt], acc[mt][nt], 0, 0, 0);
    __syncthreads();  // drains vmcnt (next tile landed) + lgkm; one barrier per K-step
    cur ^= 1;
  }

  const int gmb = m0 + wm * 64;
  const int gnb = n0 + wn * 64;
  if constexpr (MODE == MODE_T) {
    // transposed bf16 out: O[n][m], row stride M; + bias[m]
    unsigned short* O = (unsigned short*)Out + (size_t)z * oStrideZ;
    #pragma unroll
    for (int mt = 0; mt < 4; ++mt) {
      const int gm0 = gmb + mt * 16 + 4 * hi;
      const float b0 = bias[gm0], b1 = bias[gm0 + 1], b2 = bias[gm0 + 2], b3 = bias[gm0 + 3];
      #pragma unroll
      for (int nt = 0; nt < 4; ++nt) {
        const int gn = gnb + nt * 16 + l15;
        ushort4 pk;
        pk.x = f2bf(acc[mt][nt][0] + b0);
        pk.y = f2bf(acc[mt][nt][1] + b1);
        pk.z = f2bf(acc[mt][nt][2] + b2);
        pk.w = f2bf(acc[mt][nt][3] + b3);
        *reinterpret_cast<ushort4*>(O + (size_t)gn * M + gm0) = pk;
      }
    }
  } else if constexpr (MODE == MODE_NAT) {
    // natural bf16 out: O[m][n], row stride N; val*scale + optional bias[m]
    unsigned short* O = (unsigned short*)Out + (size_t)z * oStrideZ;
    #pragma unroll
    for (int mt = 0; mt < 4; ++mt) {
      const int gm0 = gmb + mt * 16 + 4 * hi;
      #pragma unroll
      for (int nt = 0; nt < 4; ++nt) {
        const int gn = gnb + nt * 16 + l15;
        #pragma unroll
        for (int e = 0; e < 4; ++e) {
          float v = acc[mt][nt][e] * scale + (bias ? bias[gm0 + e] : 0.f);
          O[(size_t)(gm0 + e) * N + gn] = f2bf(v);
        }
      }
    }
  } else {
    // fp32 out: O[m][n] = acc + bias[m] + resid[m][n]
    float* O = (float*)Out + (size_t)z * oStrideZ;
    const float* R = resid + (size_t)z * rStrideZ;
    #pragma unroll
    for (int mt = 0; mt < 4; ++mt) {
      const int gm0 = gmb + mt * 16 + 4 * hi;
      #pragma unroll
      for (int nt = 0; nt < 4; ++nt) {
        const int gn = gnb + nt * 16 + l15;
        #pragma unroll
        for (int e = 0; e < 4; ++e) {
          size_t idx = (size_t)(gm0 + e) * N + gn;
          O[idx] = acc[mt][nt][e] + bias[gm0 + e] + R[idx];
        }
      }
    }
  }
}

__global__ void ws_too_small(float* out, float v) {
  if (threadIdx.x == 0 && blockIdx.x == 0) out[0] = v;
}

extern "C" void kernel_launch(void* const* d_in, const int* in_sizes, int n_in,
                              void* d_out, int out_size, void* d_ws, size_t ws_size,
                              hipStream_t stream) {
  const float* x     = (const float*)d_in[0];
  const float* gamma = (const float*)d_in[1];
  const float* beta  = (const float*)d_in[2];
  const float* Wq    = (const float*)d_in[3];
  const float* bq    = (const float*)d_in[4];
  const float* Wk    = (const float*)d_in[5];
  const float* bk    = (const float*)d_in[6];
  const float* Wv    = (const float*)d_in[7];
  const float* bv    = (const float*)d_in[8];
  const float* Wo    = (const float*)d_in[9];
  const float* bo    = (const float*)d_in[10];
  float* out = (float*)d_out;

  unsigned char* ws = (unsigned char*)d_ws;
  unsigned short* WB  = (unsigned short*)(ws);             // [4][256][256] bf16 (q,k,v,o)
  unsigned short* hnT = (unsigned short*)(ws + 524288);    // [4][4096][256]
  unsigned short* Qt  = (unsigned short*)(ws + 8912896);   // [4][4096][256]
  unsigned short* Kt  = (unsigned short*)(ws + 17301504);  // [4][4096][256]
  unsigned short* V   = (unsigned short*)(ws + 25690112);  // [4][256][4096]
  unsigned short* Ht  = (unsigned short*)(ws + 34078720);  // [4][4096][256]
  unsigned short* S   = (unsigned short*)(ws + 42467328);  // [nb][4096][4096]

  const size_t sbase  = 42467328;
  const size_t sbytes = 33554432;
  int nb = 0;
  if (ws_size >= sbase + 4 * sbytes) nb = 4;
  else if (ws_size >= sbase + sbytes) nb = 1;
  if (nb == 0) {
    hipMemsetAsync(d_out, 0, (size_t)out_size * 4, stream);
    ws_too_small<<<1, 64, 0, stream>>>(out, (float)ws_size);
    return;
  }

  prep_weights<<<1024, 256, 0, stream>>>(Wq, Wk, Wv, Wo, WB);
  groupnorm_kernel<<<128, 256, 0, stream>>>(x, gamma, beta, hnT);

  // QKV projections: M=256 (c_out), N=4096 (pixels), K=256 (c_in); z = batch
  gemm128<MODE_T><<<dim3(32, 2, 4), 256, 0, stream>>>(
      WB, 0, hnT, 1048576, Qt, 1048576, bq, nullptr, 0, 256, 4096, 256, 1.f);
  gemm128<MODE_T><<<dim3(32, 2, 4), 256, 0, stream>>>(
      WB + 65536, 0, hnT, 1048576, Kt, 1048576, bk, nullptr, 0, 256, 4096, 256, 1.f);
  gemm128<MODE_NAT><<<dim3(32, 2, 4), 256, 0, stream>>>(
      WB + 131072, 0, hnT, 1048576, V, 1048576, bv, nullptr, 0, 256, 4096, 256, 1.f);

  for (int done = 0; done < 4; done += nb) {
    int nbc = (4 - done < nb) ? (4 - done) : nb;
    // S[i][j] = (1/16) sum_c Qt[i][c] * Kt[j][c];  M=N=4096, K=256
    gemm128<MODE_NAT><<<dim3(32, 32, nbc), 256, 0, stream>>>(
        Qt + (size_t)done * 1048576, 1048576, Kt + (size_t)done * 1048576, 1048576,
        S, 16777216, nullptr, nullptr, 0, 4096, 4096, 256, 0.0625f);
    softmax_kernel<<<dim3(4096, nbc), 256, 0, stream>>>(S, 16777216);
    // Ht[i][c] = sum_j P[i][j] * V[c][j];  M=4096 (i), N=256 (c), K=4096 (j)
    gemm128<MODE_NAT><<<dim3(2, 32, nbc), 256, 0, stream>>>(
        S, 16777216, V + (size_t)done * 1048576, 1048576,
        Ht + (size_t)done * 1048576, 1048576, nullptr, nullptr, 0, 4096, 256, 4096, 1.f);
  }

  // out[co][n] = sum_c Wo[co][c] * Ht[n][c] + bo[co] + x;  M=256, N=4096, K=256
  gemm128<MODE_OUT><<<dim3(32, 2, 4), 256, 0, stream>>>(
      WB + 196608, 0, Ht, 1048576, out, 1048576, bo, x, 1048576, 256, 4096, 256, 1.f);
}

// Round 4
// 254.507 us; speedup vs baseline: 1.4512x; 1.2358x over previous
//
#include <hip/hip_runtime.h>

typedef __attribute__((ext_vector_type(4))) float f32x4;
typedef __attribute__((ext_vector_type(8))) __bf16 bf16x8;

__device__ __forceinline__ unsigned short f2bf(float f) {
  unsigned int u = __float_as_uint(f);
  u += 0x7FFFu + ((u >> 16) & 1u);
  return (unsigned short)(u >> 16);
}

__device__ __forceinline__ void gload16(const void* g, void* l) {
  __builtin_amdgcn_global_load_lds(
      (const __attribute__((address_space(1))) void*)g,
      (__attribute__((address_space(3))) void*)l, 16, 0, 0);
}

// ---------------- weight fp32 -> bf16 ----------------
__global__ __launch_bounds__(256)
void prep_weights(const float* __restrict__ wq, const float* __restrict__ wk,
                  const float* __restrict__ wv, const float* __restrict__ wo,
                  unsigned short* __restrict__ out) {
  int i = blockIdx.x * 256 + threadIdx.x;  // 4 * 65536 total
  const float* src = (i < 65536) ? wq : (i < 131072) ? wk : (i < 196608) ? wv : wo;
  out[i] = f2bf(src[i & 65535]);
}

// ---------------- GroupNorm -> hnT [b][n][c] bf16 ----------------
__global__ __launch_bounds__(256)
void groupnorm_kernel(const float* __restrict__ x, const float* __restrict__ gamma,
                      const float* __restrict__ beta, unsigned short* __restrict__ hnT) {
  const int blk = blockIdx.x;        // b*32 + g
  const int b = blk >> 5, g = blk & 31;
  const int N = 4096;
  const float* xb = x + ((size_t)b * 256 + (size_t)g * 8) * N;
  const int tid = threadIdx.x;

  float s = 0.f, ss = 0.f;
  for (int c = 0; c < 8; ++c) {
    const float* xc = xb + (size_t)c * N;
    for (int i = tid; i < N; i += 256) { float v = xc[i]; s += v; ss += v * v; }
  }
  __shared__ float rs[4], rss[4];
  for (int m = 1; m <= 32; m <<= 1) { s += __shfl_xor(s, m); ss += __shfl_xor(ss, m); }
  const int lane = tid & 63, wid = tid >> 6;
  if (lane == 0) { rs[wid] = s; rss[wid] = ss; }
  __syncthreads();
  s  = rs[0] + rs[1] + rs[2] + rs[3];
  ss = rss[0] + rss[1] + rss[2] + rss[3];
  const float mean = s * (1.f / 32768.f);
  const float var  = ss * (1.f / 32768.f) - mean * mean;
  const float rstd = rsqrtf(var + 1e-6f);

  float gk[8], bk2[8];
  #pragma unroll
  for (int c = 0; c < 8; ++c) {
    float ga = gamma[g * 8 + c] * rstd;
    gk[c]  = ga;
    bk2[c] = beta[g * 8 + c] - mean * ga;
  }
  unsigned short* outp = hnT + (size_t)b * 256 * N + g * 8;
  for (int i = tid; i < N; i += 256) {
    union { unsigned short u[8]; uint4 v; } pk;
    #pragma unroll
    for (int c = 0; c < 8; ++c) pk.u[c] = f2bf(xb[(size_t)c * N + i] * gk[c] + bk2[c]);
    *reinterpret_cast<uint4*>(outp + (size_t)i * 256) = pk.v;
  }
}

// ---------------- fused flash attention ----------------
// Qt,Kt: [z][4096][256] bf16 (K-major). V: [z][256][4096] bf16 (natural).
// Ht out: [z][4096][256] bf16.  S^T = mfma(K,Q) swapped form; online softmax;
// P -> wave-private LDS bounce -> PV mfma.  K/V double-buffered LDS staged via
// global_load_lds (linear dest, inverse-swizzled source; swizzled reads).
__global__ __launch_bounds__(256)
void flash_attn(const unsigned short* __restrict__ Qt,
                const unsigned short* __restrict__ Kt,
                const unsigned short* __restrict__ Vp,
                unsigned short* __restrict__ Ht) {
  // LDS map: K bufs @0,@32768 (64 rows x 512B, 32 slots, slot^=(j&7))
  //          V bufs @65536,@98304 (256 rows x 128B, 8 slots, slot^=(c&7))
  //          P @131072 + w*2048 (16 rows x 128B, 8 slots, slot^=(i&7))
  //          sc @139264 + w*64 (16 f32)
  __shared__ alignas(1024) unsigned char lds[139520];
  const int tid = threadIdx.x, lane = tid & 63, w = tid >> 6;
  const int hig = lane >> 4, l15 = lane & 15;
  const int z = blockIdx.y, qt = blockIdx.x;
  const size_t zoff = (size_t)z * 1048576;
  const unsigned short* Qz = Qt + zoff;
  const unsigned short* Kz = Kt + zoff;
  const unsigned short* Vz = Vp + zoff;
  const int i0 = qt * 64 + w * 16;

  // Q fragments (B-operand: lane&15 = q-row col, hig = k-group-of-8 in c)
  bf16x8 qf[8];
  #pragma unroll
  for (int ks = 0; ks < 8; ++ks)
    qf[ks] = *reinterpret_cast<const bf16x8*>(Qz + (size_t)(i0 + l15) * 256 + ks * 32 + hig * 8);

  f32x4 o[16] = {};
  float m = -1e30f, l = 0.f;

  float* scp = (float*)(lds + 139264 + w * 64);
  unsigned char* Pw = lds + 131072 + w * 2048;

  auto stage = [&](int buf, int jt) {
    unsigned char* Kd = lds + buf * 32768 + w * 8192;
    unsigned char* Vd = lds + 65536 + buf * 32768 + w * 8192;
    #pragma unroll
    for (int g = 0; g < 8; ++g) {
      const int j = w * 16 + g * 2 + (lane >> 5);
      const unsigned short* src =
          Kz + (size_t)(jt * 64 + j) * 256 + (((lane & 31) ^ (j & 7)) << 3);
      gload16(src, Kd + g * 1024);
    }
    #pragma unroll
    for (int g = 0; g < 8; ++g) {
      const int c = w * 64 + g * 8 + (lane >> 3);
      const unsigned short* src =
          Vz + (size_t)c * 4096 + jt * 64 + (((lane & 7) ^ ((lane >> 3) & 7)) << 3);
      gload16(src, Vd + g * 1024);
    }
  };

  stage(0, 0);
  for (int jt = 0; jt < 64; ++jt) {
    asm volatile("s_waitcnt vmcnt(0)" ::: "memory");  // own stage loads landed
    __builtin_amdgcn_s_barrier();                     // all waves' loads landed
    __builtin_amdgcn_sched_barrier(0);
    const int cur = jt & 1;
    if (jt + 1 < 64) stage(cur ^ 1, jt + 1);          // prefetch; drained next iter

    const unsigned char* Kb = lds + cur * 32768;
    const unsigned char* Vb = lds + 65536 + cur * 32768;

    // QK^T swapped: sAcc[jf] rows j=16jf+4hig+e, col i=l15
    f32x4 sAcc[4] = {};
    #pragma unroll
    for (int ks = 0; ks < 8; ++ks) {
      #pragma unroll
      for (int jf = 0; jf < 4; ++jf) {
        const int jl = jf * 16 + l15;
        bf16x8 kf = *reinterpret_cast<const bf16x8*>(
            Kb + jl * 512 + (((4 * ks + hig) ^ (jl & 7)) << 4));
        sAcc[jf] = __builtin_amdgcn_mfma_f32_16x16x32_bf16(kf, qf[ks], sAcc[jf], 0, 0, 0);
      }
    }
    // online softmax over j (rows of S^T): in-lane 16 + shfl over hig bits
    float tm = -1e30f;
    #pragma unroll
    for (int jf = 0; jf < 4; ++jf) {
      sAcc[jf] *= 0.0625f;
      #pragma unroll
      for (int e = 0; e < 4; ++e) tm = fmaxf(tm, sAcc[jf][e]);
    }
    tm = fmaxf(tm, __shfl_xor(tm, 16));
    tm = fmaxf(tm, __shfl_xor(tm, 32));
    const float mnew = fmaxf(m, tm);
    const float scf = __expf(m - mnew);
    m = mnew;
    float ts = 0.f;
    ushort4 pk[4];
    #pragma unroll
    for (int jf = 0; jf < 4; ++jf) {
      float p0 = __expf(sAcc[jf][0] - mnew), p1 = __expf(sAcc[jf][1] - mnew);
      float p2 = __expf(sAcc[jf][2] - mnew), p3 = __expf(sAcc[jf][3] - mnew);
      ts += (p0 + p1) + (p2 + p3);
      pk[jf].x = f2bf(p0); pk[jf].y = f2bf(p1);
      pk[jf].z = f2bf(p2); pk[jf].w = f2bf(p3);
    }
    ts += __shfl_xor(ts, 16);
    ts += __shfl_xor(ts, 32);
    l = l * scf + ts;
    if (hig == 0) scp[l15] = scf;   // row-scale bounce (i=l15 -> i=4hig+e)
    // P^T -> P_lds: row i=l15, col bytes 32jf+8hig (ushort4), slot-swizzled
    #pragma unroll
    for (int jf = 0; jf < 4; ++jf)
      *reinterpret_cast<ushort4*>(
          Pw + l15 * 128 + (((2 * jf + (hig >> 1)) ^ (l15 & 7)) << 4) + ((hig & 1) << 3)) = pk[jf];
    f32x4 scv = *reinterpret_cast<f32x4*>(scp + hig * 4);
    #pragma unroll
    for (int nf = 0; nf < 16; ++nf) o[nf] *= scv;
    // PV: A=P (rows i), B=V (cols c), k=j
    #pragma unroll
    for (int ks = 0; ks < 2; ++ks) {
      bf16x8 pa = *reinterpret_cast<const bf16x8*>(
          Pw + l15 * 128 + (((4 * ks + hig) ^ (l15 & 7)) << 4));
      #pragma unroll
      for (int nf = 0; nf < 16; ++nf) {
        const int c = nf * 16 + l15;
        bf16x8 vb = *reinterpret_cast<const bf16x8*>(
            Vb + c * 128 + (((4 * ks + hig) ^ (l15 & 7)) << 4));
        o[nf] = __builtin_amdgcn_mfma_f32_16x16x32_bf16(pa, vb, o[nf], 0, 0, 0);
      }
    }
  }
  // epilogue: 1/l bounce, normalize, store Ht [n][c] bf16
  if (hig == 0) scp[l15] = l;
  f32x4 lv = *reinterpret_cast<f32x4*>(scp + hig * 4);
  unsigned short* Hz = Ht + zoff;
  #pragma unroll
  for (int e = 0; e < 4; ++e) {
    const float inv = 1.f / lv[e];
    const size_t rowo = (size_t)(i0 + 4 * hig + e) * 256;
    #pragma unroll
    for (int nf = 0; nf < 16; ++nf)
      Hz[rowo + nf * 16 + l15] = f2bf(o[nf][e] * inv);
  }
}

// ---------------- 128x128 MFMA GEMM, A [M][K] bf16, B [N][K] bf16 ----------------
enum { MODE_T = 0, MODE_NAT = 1, MODE_OUT = 2 };

template<int MODE>
__global__ __launch_bounds__(256)
void gemm128(const unsigned short* __restrict__ A, long aStrideZ,
             const unsigned short* __restrict__ B, long bStrideZ,
             void* __restrict__ Out, long oStrideZ,
             const float* __restrict__ bias,
             const float* __restrict__ resid, long rStrideZ,
             int M, int N, int K, float scale) {
  __shared__ alignas(1024) unsigned char lds[32768];  // [buf][A 8K | B 8K]
  const int tid  = threadIdx.x;
  const int lane = tid & 63;
  const int hi   = lane >> 4;
  const int l15  = lane & 15;
  const int wid  = tid >> 6;
  const int wm = wid >> 1, wn = wid & 1;
  const int z  = blockIdx.z;
  const int m0 = blockIdx.y * 128;
  const int n0 = blockIdx.x * 128;
  const unsigned short* Az = A + (size_t)z * aStrideZ;
  const unsigned short* Bz = B + (size_t)z * bStrideZ;

  const int c0 = wid * 2, c1 = wid * 2 + 1;
  const int rr = lane >> 2;
  const int qs = (lane & 3) ^ ((lane >> 3) & 3);
  const unsigned short* pa0 = Az + (size_t)(m0 + c0 * 16 + rr) * K + qs * 8;
  const unsigned short* pa1 = Az + (size_t)(m0 + c1 * 16 + rr) * K + qs * 8;
  const unsigned short* pb0 = Bz + (size_t)(n0 + c0 * 16 + rr) * K + qs * 8;
  const unsigned short* pb1 = Bz + (size_t)(n0 + c1 * 16 + rr) * K + qs * 8;
  unsigned char* lA0 = lds + c0 * 1024;
  unsigned char* lA1 = lds + c1 * 1024;
  unsigned char* lB0 = lds + 8192 + c0 * 1024;
  unsigned char* lB1 = lds + 8192 + c1 * 1024;

  const int slot = hi ^ ((l15 >> 1) & 3);
  int roffA[4], roffB[4];
  #pragma unroll
  for (int t = 0; t < 4; ++t) {
    roffA[t] = (wm * 64 + t * 16 + l15) * 64 + slot * 16;
    roffB[t] = 8192 + (wn * 64 + t * 16 + l15) * 64 + slot * 16;
  }

  f32x4 acc[4][4] = {};

  const int nk = K >> 5;
  gload16(pa0, lA0); gload16(pa1, lA1);
  gload16(pb0, lB0); gload16(pb1, lB1);
  __syncthreads();

  int cur = 0;
  for (int kt = 0; kt < nk; ++kt) {
    if (kt + 1 < nk) {
      const size_t ko = (size_t)(kt + 1) * 32;
      const int bo = (cur ^ 1) * 16384;
      gload16(pa0 + ko, lA0 + bo); gload16(pa1 + ko, lA1 + bo);
      gload16(pb0 + ko, lB0 + bo); gload16(pb1 + ko, lB1 + bo);
    }
    const unsigned char* base = lds + cur * 16384;
    bf16x8 af[4], bfr[4];
    #pragma unroll
    for (int t = 0; t < 4; ++t) {
      af[t]  = *reinterpret_cast<const bf16x8*>(base + roffA[t]);
      bfr[t] = *reinterpret_cast<const bf16x8*>(base + roffB[t]);
    }
    #pragma unroll
    for (int mt = 0; mt < 4; ++mt)
      #pragma unroll
      for (int nt = 0; nt < 4; ++nt)
        acc[mt][nt] = __builtin_amdgcn_mfma_f32_16x16x32_bf16(af[mt], bfr[nt], acc[mt][nt], 0, 0, 0);
    __syncthreads();
    cur ^= 1;
  }

  const int gmb = m0 + wm * 64;
  const int gnb = n0 + wn * 64;
  if constexpr (MODE == MODE_T) {
    unsigned short* O = (unsigned short*)Out + (size_t)z * oStrideZ;
    #pragma unroll
    for (int mt = 0; mt < 4; ++mt) {
      const int gm0 = gmb + mt * 16 + 4 * hi;
      const float b0 = bias[gm0], b1 = bias[gm0 + 1], b2 = bias[gm0 + 2], b3 = bias[gm0 + 3];
      #pragma unroll
      for (int nt = 0; nt < 4; ++nt) {
        const int gn = gnb + nt * 16 + l15;
        ushort4 pk;
        pk.x = f2bf(acc[mt][nt][0] + b0);
        pk.y = f2bf(acc[mt][nt][1] + b1);
        pk.z = f2bf(acc[mt][nt][2] + b2);
        pk.w = f2bf(acc[mt][nt][3] + b3);
        *reinterpret_cast<ushort4*>(O + (size_t)gn * M + gm0) = pk;
      }
    }
  } else if constexpr (MODE == MODE_NAT) {
    unsigned short* O = (unsigned short*)Out + (size_t)z * oStrideZ;
    #pragma unroll
    for (int mt = 0; mt < 4; ++mt) {
      const int gm0 = gmb + mt * 16 + 4 * hi;
      #pragma unroll
      for (int nt = 0; nt < 4; ++nt) {
        const int gn = gnb + nt * 16 + l15;
        #pragma unroll
        for (int e = 0; e < 4; ++e) {
          float v = acc[mt][nt][e] * scale + (bias ? bias[gm0 + e] : 0.f);
          O[(size_t)(gm0 + e) * N + gn] = f2bf(v);
        }
      }
    }
  } else {
    float* O = (float*)Out + (size_t)z * oStrideZ;
    const float* R = resid + (size_t)z * rStrideZ;
    #pragma unroll
    for (int mt = 0; mt < 4; ++mt) {
      const int gm0 = gmb + mt * 16 + 4 * hi;
      #pragma unroll
      for (int nt = 0; nt < 4; ++nt) {
        const int gn = gnb + nt * 16 + l15;
        #pragma unroll
        for (int e = 0; e < 4; ++e) {
          size_t idx = (size_t)(gm0 + e) * N + gn;
          O[idx] = acc[mt][nt][e] + bias[gm0 + e] + R[idx];
        }
      }
    }
  }
}

__global__ void ws_too_small(float* out, float v) {
  if (threadIdx.x == 0 && blockIdx.x == 0) out[0] = v;
}

extern "C" void kernel_launch(void* const* d_in, const int* in_sizes, int n_in,
                              void* d_out, int out_size, void* d_ws, size_t ws_size,
                              hipStream_t stream) {
  const float* x     = (const float*)d_in[0];
  const float* gamma = (const float*)d_in[1];
  const float* beta  = (const float*)d_in[2];
  const float* Wq    = (const float*)d_in[3];
  const float* bq    = (const float*)d_in[4];
  const float* Wk    = (const float*)d_in[5];
  const float* bk    = (const float*)d_in[6];
  const float* Wv    = (const float*)d_in[7];
  const float* bv    = (const float*)d_in[8];
  const float* Wo    = (const float*)d_in[9];
  const float* bo    = (const float*)d_in[10];
  float* out = (float*)d_out;

  unsigned char* ws = (unsigned char*)d_ws;
  unsigned short* WB  = (unsigned short*)(ws);             // [4][256][256] bf16 (q,k,v,o)
  unsigned short* hnT = (unsigned short*)(ws + 524288);    // [4][4096][256]
  unsigned short* Qt  = (unsigned short*)(ws + 8912896);   // [4][4096][256]
  unsigned short* Kt  = (unsigned short*)(ws + 17301504);  // [4][4096][256]
  unsigned short* V   = (unsigned short*)(ws + 25690112);  // [4][256][4096]
  unsigned short* Ht  = (unsigned short*)(ws + 34078720);  // [4][4096][256]

  if (ws_size < 42467328) {
    hipMemsetAsync(d_out, 0, (size_t)out_size * 4, stream);
    ws_too_small<<<1, 64, 0, stream>>>(out, (float)ws_size);
    return;
  }

  prep_weights<<<1024, 256, 0, stream>>>(Wq, Wk, Wv, Wo, WB);
  groupnorm_kernel<<<128, 256, 0, stream>>>(x, gamma, beta, hnT);

  // QKV projections: M=256 (c_out), N=4096 (pixels), K=256 (c_in); z = batch
  gemm128<MODE_T><<<dim3(32, 2, 4), 256, 0, stream>>>(
      WB, 0, hnT, 1048576, Qt, 1048576, bq, nullptr, 0, 256, 4096, 256, 1.f);
  gemm128<MODE_T><<<dim3(32, 2, 4), 256, 0, stream>>>(
      WB + 65536, 0, hnT, 1048576, Kt, 1048576, bk, nullptr, 0, 256, 4096, 256, 1.f);
  gemm128<MODE_NAT><<<dim3(32, 2, 4), 256, 0, stream>>>(
      WB + 131072, 0, hnT, 1048576, V, 1048576, bv, nullptr, 0, 256, 4096, 256, 1.f);

  // fused attention: Ht[n][c] = softmax(Qt.Kt^T/16) @ V^T
  flash_attn<<<dim3(64, 4), 256, 0, stream>>>(Qt, Kt, V, Ht);

  // out[co][n] = sum_c Wo[co][c] * Ht[n][c] + bo[co] + x;  M=256, N=4096, K=256
  gemm128<MODE_OUT><<<dim3(32, 2, 4), 256, 0, stream>>>(
      WB + 196608, 0, Ht, 1048576, out, 1048576, bo, x, 1048576, 256, 4096, 256, 1.f);
}